// Round 1
// 261.967 us; speedup vs baseline: 1.0428x; 1.0428x over previous
//
#include <hip/hip_runtime.h>

#define NTHREADS 256

__device__ __forceinline__ int reflect128(int p) {
    p = (p < 0) ? (-p - 1) : p;
    p = (p >= 128) ? (255 - p) : p;
    return p;
}

// Per output phase j: 3 consecutive nonzero taps out of 5.
// cc0/cs0 apply to the G0-pair source (Yl or lh), cc1/cs1 to the G1-pair (hl or hh).
__constant__ int   cs0[4] = {2, 1, 1, 0};
__constant__ int   cs1[4] = {1, 2, 0, 1};
__constant__ float cc0[4][3] = {
    { 0.760272369066126f, -0.0883294244510729f,  0.0351638365171441f},
    { 0.233890320607236f,  0.587518297723561f,  -0.114301837144249f},
    {-0.114301837144249f,  0.587518297723561f,   0.233890320607236f},
    { 0.0351638365171441f, -0.0883294244510729f, 0.760272369066126f}};
__constant__ float cc1[4][3] = {
    { 0.233890320607236f,  0.587518297723561f,  -0.114301837144249f},
    {-0.760272369066126f,  0.0883294244510729f, -0.0351638365171441f},
    {-0.0351638365171441f, 0.0883294244510729f, -0.760272369066126f},
    {-0.114301837144249f,  0.587518297723561f,   0.233890320607236f}};

__global__ __launch_bounds__(NTHREADS, 6)
void dtcwt_inv_kernel(const float* __restrict__ Yl,
                      const float* __restrict__ Yhr,
                      const float* __restrict__ Yhi,
                      float* __restrict__ out)
{
    const int tid   = threadIdx.x;
    const int ct    = blockIdx.x;   // col tile 0..3
    const int rt    = blockIdx.y;   // row tile 0..3
    const int plane = blockIdx.z;   // 0..511

    const int OR0 = rt * 64, OC0 = ct * 64;
    const int i0r = OR0 >> 2, i0c = OC0 >> 2;
    const int yrb = 2 * i0r - 4;    // raw first y row of the 40-row window (even)
    const int icb = 2 * i0c - 4;    // raw first input col of the 40-col window (even)

    const float* yl = Yl + (size_t)plane * (128 * 128);
    const float* hr = Yhr + (size_t)plane * 6 * 4096;
    const float* hi = Yhi + (size_t)plane * 6 * 4096;

    // natural-order staging (taps read at stride-2 dwords -> 2-way max = free)
    __shared__ float sLh[40][40];
    __shared__ float sHl[40][40];
    __shared__ float sHh[40][40];
    __shared__ float sYl[40][40];   // dense-staged Yl window (kills stride-2 global reads)

    const float RS2 = 0.70710678118654752440f;  // 1/sqrt(2)

    // ---- Phase A1: stage Yl window (40x40, reflected) ----
    for (int e = tid; e < 1600; e += NTHREADS) {
        const int t = e / 40;
        const int u = e - t * 40;
        const int r2 = reflect128(yrb + t);
        const int c2 = reflect128(icb + u);
        sYl[t][u] = yl[r2 * 128 + c2];
    }

    // ---- Phase A2: c2q per 2x2 quad; 12 global loads -> 12 staged values ----
    for (int e = tid; e < 400; e += NTHREADS) {
        const int t2 = e / 20;
        const int u2 = e - t2 * 20;
        const int ar = i0r - 2 + t2;
        const int ac = i0c - 2 + u2;
        const int oobr = (ar < 0) | (ar >= 64);
        const int oobc = (ac < 0) | (ac >= 64);
        const int r2 = oobr ? ((ar < 0) ? (-ar - 1) : (127 - ar)) : ar;
        const int c2 = oobc ? ((ac < 0) ? (-ac - 1) : (127 - ac)) : ac;
        const int off = r2 * 64 + c2;
        const float ar0 = hr[off], ar1 = hr[4096 + off], ar2 = hr[2 * 4096 + off];
        const float ar3 = hr[3 * 4096 + off], ar4 = hr[4 * 4096 + off], ar5 = hr[5 * 4096 + off];
        const float ai0 = hi[off], ai1 = hi[4096 + off], ai2 = hi[2 * 4096 + off];
        const float ai3 = hi[3 * 4096 + off], ai4 = hi[4 * 4096 + off], ai5 = hi[5 * 4096 + off];
#pragma unroll
        for (int dt = 0; dt < 2; ++dt) {
#pragma unroll
            for (int du = 0; du < 2; ++du) {
                const int p = dt ^ oobr;            // reflection flips sample parity
                const int q = du ^ oobc;
                const float sA = (p & q) ? -RS2 : RS2;
                const float sB = (p & (q ^ 1)) ? -RS2 : RS2;
                float b0, b5, b2v, b3, b1, b4;
                if (p == q) { b0 = ar0; b5 = ar5; b2v = ar2; b3 = ar3; b1 = ar1; b4 = ar4; }
                else        { b0 = ai0; b5 = ai5; b2v = ai2; b3 = ai3; b1 = ai1; b4 = ai4; }
                const int t = 2 * t2 + dt, u = 2 * u2 + du;
                sLh[t][u] = sA * b0 + sB * b5;
                sHl[t][u] = sA * b2v + sB * b3;
                sHh[t][u] = sA * b1 + sB * b4;
            }
        }
    }
    __syncthreads();

    // ---- Phase B+C fused: each thread owns one column and a 16-row output strip.
    //      Row-filter its 14-row y1/y2 window into registers, then column-filter. ----
    const int c  = tid & 63;        // output column within tile
    const int g  = tid >> 6;        // 16-row output strip (m in [4g, 4g+4))
    const int jc = c & 3;
    const int q2 = c >> 2;
    const float a0  = cc0[jc][0], a1  = cc0[jc][1], a2  = cc0[jc][2];
    const float b0w = cc1[jc][0], b1w = cc1[jc][1], b2w = cc1[jc][2];
    const int ub0 = 2 * q2 + (jc & 1) + 2 * cs0[jc];          // first G0 tap col (staged u)
    const int ub1 = 2 * q2 + ((jc & 1) ^ 1) + 2 * cs1[jc];    // first G1 tap col

    const int tb = 8 * g;           // y rows needed: [tb+1, tb+14]
    float y1v[14], y2v[14];
#pragma unroll
    for (int k = 0; k < 14; ++k) {
        const int t = tb + 1 + k;
        y1v[k] = sYl[t][ub0] * a0  + sYl[t][ub0 + 2] * a1  + sYl[t][ub0 + 4] * a2
               + sHl[t][ub1] * b0w + sHl[t][ub1 + 2] * b1w + sHl[t][ub1 + 4] * b2w;
        y2v[k] = sLh[t][ub0] * a0  + sLh[t][ub0 + 2] * a1  + sLh[t][ub0 + 4] * a2
               + sHh[t][ub1] * b0w + sHh[t][ub1 + 2] * b1w + sHh[t][ub1 + 4] * b2w;
    }

    float* op = out + ((size_t)plane * 256 + OR0 + 16 * g) * 256 + OC0 + c;
#pragma unroll
    for (int j = 0; j < 4; ++j) {
        const int p0 = j & 1, p1 = p0 ^ 1;
        const int r0 = p0 + 2 * cs0[j];   // y1 tap rows: 2m + r0 + {0,2,4}
        const int r1 = p1 + 2 * cs1[j];
        const float d0 = cc0[j][0], d1 = cc0[j][1], d2 = cc0[j][2];
        const float e0 = cc1[j][0], e1 = cc1[j][1], e2 = cc1[j][2];
#pragma unroll
        for (int mm = 0; mm < 4; ++mm) {
            // absolute staged tap row = 8g + 2mm + r0 + {0,2,4}; reg index = that - (8g+1)
            const int k0 = 2 * mm + r0 - 1;
            const int k1 = 2 * mm + r1 - 1;
            const float acc = y1v[k0] * d0 + y1v[k0 + 2] * d1 + y1v[k0 + 4] * d2
                            + y2v[k1] * e0 + y2v[k1 + 2] * e1 + y2v[k1 + 4] * e2;
            op[(size_t)(4 * mm + j) * 256] = acc;
        }
    }
}

extern "C" void kernel_launch(void* const* d_in, const int* in_sizes, int n_in,
                              void* d_out, int out_size, void* d_ws, size_t ws_size,
                              hipStream_t stream) {
    const float* Yl  = (const float*)d_in[0];
    const float* Yhr = (const float*)d_in[1];
    const float* Yhi = (const float*)d_in[2];
    float* out = (float*)d_out;

    const int planes = in_sizes[0] / (128 * 128);   // B*C = 512
    dim3 grid(4, 4, planes);
    dtcwt_inv_kernel<<<grid, NTHREADS, 0, stream>>>(Yl, Yhr, Yhi, out);
}